// Round 15
// baseline (33.281 us; speedup 1.0000x reference)
//
#include <hip/hip_runtime.h>
#include <hip/hip_bf16.h>
#include <math.h>

typedef __attribute__((ext_vector_type(8)))  short bf16x8;
typedef __attribute__((ext_vector_type(16))) float f32x16;
typedef unsigned int u32;

#define KAPPA (1.0f/61.0f)
#define NBLK 512           // 32768 rows / 64 rows-per-block
// swap bits 2<->3 of a 5-bit row index (pre-D row -> B-frag k-order fixup)
#define SWAP23(r) (((r) & 19) | (((r) & 4) << 1) | (((r) & 8) >> 1))

__device__ __forceinline__ unsigned short f2bf(float f) {
    u32 x = __float_as_uint(f);
    x += 0x7fffu + ((x >> 16) & 1u);               // RNE
    return (unsigned short)(x >> 16);
}
__device__ __forceinline__ float fast_rcp(float v) {
#if __has_builtin(__builtin_amdgcn_rcpf)
    return __builtin_amdgcn_rcpf(v);
#else
    return 1.0f / v;
#endif
}
__device__ __forceinline__ float exp2_fast(float v) {
#if __has_builtin(__builtin_amdgcn_exp2f)
    return __builtin_amdgcn_exp2f(v);              // raw v_exp_f32
#else
    return exp2f(v);
#endif
}
__device__ __forceinline__ u32 pack_bf16(float lo, float hi) {
    __hip_bfloat162 p = __float22bfloat162_rn(make_float2(lo, hi));  // v_cvt_pk path
    return *reinterpret_cast<u32*>(&p);
}

// ---------------------------------------------------------------------------
// Kernel 1: precompute MFMA operand fragments (all sample-independent) and
// zero the two output accumulators (re-zeroed every launch; stream order
// guarantees this completes before torsion_main's atomicAdds).
//  V  frags [16384]: f=(kkg*8+ptile)*64+lane -> A-frag of 4*V^T:
//       row p = ptile*32+(lane&31), k h = kkg*16+(lane>>5)*8+i
//       V[h][p] = 4 * W1[l][h]*W2[h][c], p=l*35+c (pad 245->256).
//  Wt frags [1024]: f=htile*64+lane -> A-frag of [W1^T | b1] with SWAP23-
//       permuted rows, so the pre-MFMA's packed D output is directly the
//       main-GEMM B-fragment (verified r9).
// ---------------------------------------------------------------------------
__global__ void build_v(const float* __restrict__ W1, const float* __restrict__ W2,
                        const float* __restrict__ b1,
                        bf16x8* __restrict__ V, bf16x8* __restrict__ Wt,
                        float* __restrict__ out) {
    int t = blockIdx.x * blockDim.x + threadIdx.x;
    if (t == 0) { out[0] = 0.0f; out[1] = 0.0f; }
    if (t < 16384) {
        int lane = t & 63, ptile = (t >> 6) & 7, kkg = t >> 9;
        int p  = ptile * 32 + (lane & 31);
        int hb = kkg * 16 + (lane >> 5) * 8;
        bool valid = (p < 245);
        int l7 = valid ? p / 35 : 0;
        int c  = valid ? p - l7 * 35 : 0;
        bf16x8 v;
#pragma unroll
        for (int i = 0; i < 8; ++i) {
            int h = hb + i;
            v[i] = valid ? (short)f2bf(4.0f * W1[l7 * 512 + h] * W2[h * 35 + c]) : (short)0;
        }
        V[t] = v;
    } else if (t < 16384 + 1024) {
        int f = t - 16384;
        int lane = f & 63, htile = f >> 6;
        int row = lane & 31;
        int h = htile * 32 + SWAP23(row);
        bf16x8 v;
#pragma unroll
        for (int i = 0; i < 8; ++i) v[i] = 0;
        if (lane < 32) {
#pragma unroll
            for (int l = 0; l < 7; ++l) v[l] = (short)f2bf(W1[l * 512 + h]);
            v[7] = (short)f2bf(b1[h]);
        }
        Wt[f] = v;
    }
}

// ---------------------------------------------------------------------------
// Kernel 2: main — r13 champion structure (64-h chunks, Wt register-prefetch,
// g = t*r^2 with t = 2^(-2.8853901*|pre|), 4 folded into V) with the final
// reduction fused via two per-block atomicAdds into d_out (no fence, no
// ticket, no third kernel). 512 blocks x 256 threads (4 waves); block =
// 64 samples x 256 p; chunk order: (1) batch V loads + Wt prefetch,
// (2) pre_pack(c+1), (3) MFMA cluster, (4) store_g, barrier.
// ---------------------------------------------------------------------------
__global__ __launch_bounds__(256, 3)
void torsion_main(const float* __restrict__ x,
                  const bf16x8* __restrict__ V, const bf16x8* __restrict__ Wt,
                  float* __restrict__ out) {
    __shared__ __align__(16) u32 Gb[2][8][64 * 4];   // [buf][ks*2+rt][lane dwords] = 16KB
    __shared__ float red[4][2][32];

    const int tid  = threadIdx.x;
    const int lane = tid & 63;
    const int w    = tid >> 6;
    const int blk  = blockIdx.x;
    const int rt   = w & 1;      // sample tile this wave's pre covers
    const int ht   = w >> 1;     // h-subtile (0..1) within chunk

    // x B-frag (once): col = sample, lo half k=0..6 -> x, k=7 -> 1.0; hi half 0
    bf16x8 xf;
#pragma unroll
    for (int i = 0; i < 8; ++i) xf[i] = 0;
    if (lane < 32) {
        const float* xp = x + ((size_t)blk * 64 + rt * 32 + lane) * 7;
#pragma unroll
        for (int l = 0; l < 7; ++l) xf[l] = (short)f2bf(xp[l]);
        xf[7] = (short)f2bf(1.0f);
    }

    f32x16 acc[2][2];
#pragma unroll
    for (int pt = 0; pt < 2; ++pt)
#pragma unroll
        for (int r2 = 0; r2 < 2; ++r2)
#pragma unroll
            for (int e = 0; e < 16; ++e) acc[pt][r2][e] = 0.0f;

    // pre^T tile -> 8 packed dwords of g (wf passed in, prefetched).
    // With SWAP23-permuted Wt, d[0..3] IS the B-frag for kstep 2ht,
    // d[4..7] for kstep 2ht+1. g = t*r^2 (the 4 lives in V).
    auto pre_pack = [&](bf16x8 wf, u32 d[8]) {
        f32x16 p;
#pragma unroll
        for (int e = 0; e < 16; ++e) p[e] = 0.0f;
        p = __builtin_amdgcn_mfma_f32_32x32x16_bf16(wf, xf, p, 0, 0, 0);
#pragma unroll
        for (int j = 0; j < 8; ++j) {
            float t0 = exp2_fast(-2.8853901f * fabsf(p[2 * j]));
            float r0 = fast_rcp(1.0f + t0);
            float g0 = t0 * r0 * r0;
            float t1 = exp2_fast(-2.8853901f * fabsf(p[2 * j + 1]));
            float r1 = fast_rcp(1.0f + t1);
            float g1 = t1 * r1 * r1;
            d[j] = pack_bf16(g0, g1);
        }
    };
    // store: two contiguous conflict-free ds_write_b128 (no scatter)
    auto store_g = [&](int buf, const u32 d[8]) {
        *reinterpret_cast<uint4*>(&Gb[buf][(2 * ht + 0) * 2 + rt][lane * 4]) =
            make_uint4(d[0], d[1], d[2], d[3]);
        *reinterpret_cast<uint4*>(&Gb[buf][(2 * ht + 1) * 2 + rt][lane * 4]) =
            make_uint4(d[4], d[5], d[6], d[7]);
    };

    // prologue: chunk-0 pre from Wt(0); prefetch Wt(1) into wfn
    bf16x8 wfn;
    {
        bf16x8 wf0 = Wt[(0 * 2 + ht) * 64 + lane];
        wfn = Wt[(1 * 2 + ht) * 64 + lane];
        u32 d0[8];
        pre_pack(wf0, d0);
        store_g(0, d0);
    }
    __syncthreads();

    for (int c = 0; c < 8; ++c) {
        const int buf = c & 1;

        // (1) issue ALL this chunk's V loads back-to-back + Wt(c+2) prefetch
        bf16x8 vreg[8];
#pragma unroll
        for (int ks = 0; ks < 4; ++ks) {
            const int fb = ((c * 4 + ks) * 8 + 2 * w) * 64 + lane;
            vreg[2 * ks]     = V[fb];
            vreg[2 * ks + 1] = V[fb + 64];
        }
        bf16x8 wf2;
        if (c < 6) wf2 = Wt[((c + 2) * 2 + ht) * 64 + lane];

        // (2) next chunk's pre from PREFETCHED wfn
        u32 dn[8];
        if (c < 7) pre_pack(wfn, dn);

        // (3) MFMA cluster (LDS reads issue before any new LDS writes)
        __builtin_amdgcn_s_setprio(1);
#pragma unroll
        for (int ks = 0; ks < 4; ++ks) {
            bf16x8 g0 = *reinterpret_cast<const bf16x8*>(&Gb[buf][ks * 2 + 0][lane * 4]);
            bf16x8 g1 = *reinterpret_cast<const bf16x8*>(&Gb[buf][ks * 2 + 1][lane * 4]);
            acc[0][0] = __builtin_amdgcn_mfma_f32_32x32x16_bf16(vreg[2 * ks],     g0, acc[0][0], 0, 0, 0);
            acc[0][1] = __builtin_amdgcn_mfma_f32_32x32x16_bf16(vreg[2 * ks],     g1, acc[0][1], 0, 0, 0);
            acc[1][0] = __builtin_amdgcn_mfma_f32_32x32x16_bf16(vreg[2 * ks + 1], g0, acc[1][0], 0, 0, 0);
            acc[1][1] = __builtin_amdgcn_mfma_f32_32x32x16_bf16(vreg[2 * ks + 1], g1, acc[1][1], 0, 0, 0);
        }
        __builtin_amdgcn_s_setprio(0);

        // (4) publish next chunk's G, rotate Wt prefetch, then barrier
        if (c < 7) store_g(buf ^ 1, dn);
        wfn = wf2;
        __syncthreads();
    }

    // ---- epilogue: D[p][sample]: col = sample; lane & lane^32 share a sample.
#pragma unroll
    for (int r2 = 0; r2 < 2; ++r2) {
        float s = 0.0f;
#pragma unroll
        for (int pt = 0; pt < 2; ++pt)
#pragma unroll
            for (int e = 0; e < 16; ++e) s += acc[pt][r2][e] * acc[pt][r2][e];
        s += __shfl_xor(s, 32);
        if (lane < 32) red[w][r2][lane] = s;
    }
    __syncthreads();

    if (tid < 64) {
        const int li = tid & 31, rr = tid >> 5;
        float q = 6.0f * (red[0][rr][li] + red[1][rr][li] + red[2][rr][li] + red[3][rr][li]);
        float n = sqrtf(q + 1e-10f);
        float d = n - KAPPA;
        float a = d * d, b = n;
#pragma unroll
        for (int m = 1; m <= 32; m <<= 1) {
            a += __shfl_xor(a, m);
            b += __shfl_xor(b, m);
        }
        if (tid == 0) {
            // fused reduction: device-scope float atomics into d_out
            // (zeroed by build_v this launch; no fence/ticket needed)
            atomicAdd(&out[0], a * (1.0f / 32768.0f));
            atomicAdd(&out[1], b * (1.0f / 32768.0f));
        }
    }
}

// ---------------------------------------------------------------------------
extern "C" void kernel_launch(void* const* d_in, const int* in_sizes, int n_in,
                              void* d_out, int out_size, void* d_ws, size_t ws_size,
                              hipStream_t stream) {
    const float* x  = (const float*)d_in[0];
    const float* W1 = (const float*)d_in[1];
    const float* b1 = (const float*)d_in[2];
    const float* W2 = (const float*)d_in[3];
    // b2 (d_in[4]) unused: the Jacobian kills the bias.

    bf16x8* V  = (bf16x8*)d_ws;                // 16384 frags * 16 B = 256 KB
    bf16x8* Wt = V + 16384;                    // 1024 frags * 16 B = 16 KB
    float*  out = (float*)d_out;

    build_v<<<68, 256, 0, stream>>>(W1, W2, b1, V, Wt, out);
    torsion_main<<<NBLK, 256, 0, stream>>>(x, V, Wt, out);
}

// Round 16
// 24.363 us; speedup vs baseline: 1.3661x; 1.3661x over previous
//
#include <hip/hip_runtime.h>
#include <hip/hip_bf16.h>
#include <math.h>

typedef __attribute__((ext_vector_type(8)))  short bf16x8;
typedef __attribute__((ext_vector_type(16))) float f32x16;
typedef unsigned int u32;

#define KAPPA (1.0f/61.0f)
#define NBLK 512           // 32768 rows / 64 rows-per-block
// swap bits 2<->3 of a 5-bit row index (pre-D row -> B-frag k-order fixup)
#define SWAP23(r) (((r) & 19) | (((r) & 4) << 1) | (((r) & 8) >> 1))

__device__ __forceinline__ unsigned short f2bf(float f) {
    u32 x = __float_as_uint(f);
    x += 0x7fffu + ((x >> 16) & 1u);               // RNE
    return (unsigned short)(x >> 16);
}
__device__ __forceinline__ float fast_rcp(float v) {
#if __has_builtin(__builtin_amdgcn_rcpf)
    return __builtin_amdgcn_rcpf(v);
#else
    return 1.0f / v;
#endif
}
__device__ __forceinline__ float exp2_fast(float v) {
#if __has_builtin(__builtin_amdgcn_exp2f)
    return __builtin_amdgcn_exp2f(v);              // raw v_exp_f32
#else
    return exp2f(v);
#endif
}
__device__ __forceinline__ u32 pack_bf16(float lo, float hi) {
    __hip_bfloat162 p = __float22bfloat162_rn(make_float2(lo, hi));  // v_cvt_pk path
    return *reinterpret_cast<u32*>(&p);
}

// ---------------------------------------------------------------------------
// Kernel 1: precompute MFMA operand fragments (all sample-independent).
//  V  frags [16384]: f=(kkg*8+ptile)*64+lane -> A-frag of 4*V^T:
//       row p = ptile*32+(lane&31), k h = kkg*16+(lane>>5)*8+i
//       V[h][p] = 4 * W1[l][h]*W2[h][c], p=l*35+c (pad 245->256).
//       The 4 is the folded constant from g = 4*t*r^2 (J invariant).
//  Wt frags [1024]: f=htile*64+lane -> A-frag of [W1^T | b1] with SWAP23-
//       permuted rows (row r -> h = htile*32 + SWAP23(r)), so the pre-MFMA's
//       packed D output is directly the main-GEMM B-fragment (verified r9).
// ---------------------------------------------------------------------------
__global__ void build_v(const float* __restrict__ W1, const float* __restrict__ W2,
                        const float* __restrict__ b1,
                        bf16x8* __restrict__ V, bf16x8* __restrict__ Wt) {
    int t = blockIdx.x * blockDim.x + threadIdx.x;
    if (t < 16384) {
        int lane = t & 63, ptile = (t >> 6) & 7, kkg = t >> 9;
        int p  = ptile * 32 + (lane & 31);
        int hb = kkg * 16 + (lane >> 5) * 8;
        bool valid = (p < 245);
        int l7 = valid ? p / 35 : 0;
        int c  = valid ? p - l7 * 35 : 0;
        bf16x8 v;
#pragma unroll
        for (int i = 0; i < 8; ++i) {
            int h = hb + i;
            v[i] = valid ? (short)f2bf(4.0f * W1[l7 * 512 + h] * W2[h * 35 + c]) : (short)0;
        }
        V[t] = v;
    } else if (t < 16384 + 1024) {
        int f = t - 16384;
        int lane = f & 63, htile = f >> 6;
        int row = lane & 31;
        int h = htile * 32 + SWAP23(row);
        bf16x8 v;
#pragma unroll
        for (int i = 0; i < 8; ++i) v[i] = 0;
        if (lane < 32) {
#pragma unroll
            for (int l = 0; l < 7; ++l) v[l] = (short)f2bf(W1[l * 512 + h]);
            v[7] = (short)f2bf(b1[h]);
        }
        Wt[f] = v;
    }
}

// ---------------------------------------------------------------------------
// Kernel 2: main — r13 champion + V one-chunk-ahead double-buffered prefetch.
// 512 blocks x 256 threads (4 waves); block = 64 samples x 256 p. Wave w:
// phase A pre-tile (ht=w>>1, rt=w&1); phase B ptiles {2w,2w+1} x both sample
// tiles (acc[2][2] = 64 VGPR). Chunk = 64 h, double-buffered G, one barrier
// per chunk. Per chunk c: (1) issue V(c+1) loads into vreg[(c+1)&1] — a full
// chunk ahead, latency fully hidden across the barrier; (2) pre_pack(c+1)
// from register-prefetched Wt; (3) MFMA cluster consumes vreg[c&1] (landed);
// (4) store_g, barrier. Loop fully unrolled -> all buffer indices static.
// launch_bounds(256,2): grid already limits to 2 blocks/CU; lifting the VGPR
// cap to fit the doubled vreg costs no occupancy.
// ---------------------------------------------------------------------------
__global__ __launch_bounds__(256, 2)
void torsion_main(const float* __restrict__ x,
                  const bf16x8* __restrict__ V, const bf16x8* __restrict__ Wt,
                  float* __restrict__ partials) {
    __shared__ __align__(16) u32 Gb[2][8][64 * 4];   // [buf][ks*2+rt][lane dwords] = 16KB
    __shared__ float red[4][2][32];

    const int tid  = threadIdx.x;
    const int lane = tid & 63;
    const int w    = tid >> 6;
    const int blk  = blockIdx.x;
    const int rt   = w & 1;      // sample tile this wave's pre covers
    const int ht   = w >> 1;     // h-subtile (0..1) within chunk

    // x B-frag (once): col = sample, lo half k=0..6 -> x, k=7 -> 1.0; hi half 0
    bf16x8 xf;
#pragma unroll
    for (int i = 0; i < 8; ++i) xf[i] = 0;
    if (lane < 32) {
        const float* xp = x + ((size_t)blk * 64 + rt * 32 + lane) * 7;
#pragma unroll
        for (int l = 0; l < 7; ++l) xf[l] = (short)f2bf(xp[l]);
        xf[7] = (short)f2bf(1.0f);
    }

    f32x16 acc[2][2];
#pragma unroll
    for (int pt = 0; pt < 2; ++pt)
#pragma unroll
        for (int r2 = 0; r2 < 2; ++r2)
#pragma unroll
            for (int e = 0; e < 16; ++e) acc[pt][r2][e] = 0.0f;

    // pre^T tile -> 8 packed dwords of g (wf passed in, prefetched).
    // With SWAP23-permuted Wt, d[0..3] IS the B-frag for kstep 2ht,
    // d[4..7] for kstep 2ht+1. g = t*r^2 (the 4 lives in V).
    auto pre_pack = [&](bf16x8 wf, u32 d[8]) {
        f32x16 p;
#pragma unroll
        for (int e = 0; e < 16; ++e) p[e] = 0.0f;
        p = __builtin_amdgcn_mfma_f32_32x32x16_bf16(wf, xf, p, 0, 0, 0);
#pragma unroll
        for (int j = 0; j < 8; ++j) {
            float t0 = exp2_fast(-2.8853901f * fabsf(p[2 * j]));
            float r0 = fast_rcp(1.0f + t0);
            float g0 = t0 * r0 * r0;
            float t1 = exp2_fast(-2.8853901f * fabsf(p[2 * j + 1]));
            float r1 = fast_rcp(1.0f + t1);
            float g1 = t1 * r1 * r1;
            d[j] = pack_bf16(g0, g1);
        }
    };
    // store: two contiguous conflict-free ds_write_b128 (no scatter)
    auto store_g = [&](int buf, const u32 d[8]) {
        *reinterpret_cast<uint4*>(&Gb[buf][(2 * ht + 0) * 2 + rt][lane * 4]) =
            make_uint4(d[0], d[1], d[2], d[3]);
        *reinterpret_cast<uint4*>(&Gb[buf][(2 * ht + 1) * 2 + rt][lane * 4]) =
            make_uint4(d[4], d[5], d[6], d[7]);
    };

    // V double-buffer: vreg[c&1] holds chunk c's frags (issued one chunk early)
    bf16x8 vreg[2][8];

    // prologue: issue chunk-0 V loads; chunk-0 pre from Wt(0); prefetch Wt(1)
    bf16x8 wfn;
    {
#pragma unroll
        for (int ks = 0; ks < 4; ++ks) {
            const int fb = (ks * 8 + 2 * w) * 64 + lane;
            vreg[0][2 * ks]     = V[fb];
            vreg[0][2 * ks + 1] = V[fb + 64];
        }
        bf16x8 wf0 = Wt[(0 * 2 + ht) * 64 + lane];
        wfn = Wt[(1 * 2 + ht) * 64 + lane];
        u32 d0[8];
        pre_pack(wf0, d0);
        store_g(0, d0);
    }
    __syncthreads();

#pragma unroll
    for (int c = 0; c < 8; ++c) {
        const int buf = c & 1;

        // (1) issue NEXT chunk's V loads (land across the barrier; zero
        //     exposure) + Wt(c+2) register prefetch
        if (c < 7) {
#pragma unroll
            for (int ks = 0; ks < 4; ++ks) {
                const int fb = (((c + 1) * 4 + ks) * 8 + 2 * w) * 64 + lane;
                vreg[buf ^ 1][2 * ks]     = V[fb];
                vreg[buf ^ 1][2 * ks + 1] = V[fb + 64];
            }
        }
        bf16x8 wf2;
        if (c < 6) wf2 = Wt[((c + 2) * 2 + ht) * 64 + lane];

        // (2) next chunk's pre from PREFETCHED wfn
        u32 dn[8];
        if (c < 7) pre_pack(wfn, dn);

        // (3) MFMA cluster consuming vreg[buf] (issued last chunk; landed)
        __builtin_amdgcn_s_setprio(1);
#pragma unroll
        for (int ks = 0; ks < 4; ++ks) {
            bf16x8 g0 = *reinterpret_cast<const bf16x8*>(&Gb[buf][ks * 2 + 0][lane * 4]);
            bf16x8 g1 = *reinterpret_cast<const bf16x8*>(&Gb[buf][ks * 2 + 1][lane * 4]);
            acc[0][0] = __builtin_amdgcn_mfma_f32_32x32x16_bf16(vreg[buf][2 * ks],     g0, acc[0][0], 0, 0, 0);
            acc[0][1] = __builtin_amdgcn_mfma_f32_32x32x16_bf16(vreg[buf][2 * ks],     g1, acc[0][1], 0, 0, 0);
            acc[1][0] = __builtin_amdgcn_mfma_f32_32x32x16_bf16(vreg[buf][2 * ks + 1], g0, acc[1][0], 0, 0, 0);
            acc[1][1] = __builtin_amdgcn_mfma_f32_32x32x16_bf16(vreg[buf][2 * ks + 1], g1, acc[1][1], 0, 0, 0);
        }
        __builtin_amdgcn_s_setprio(0);

        // (4) publish next chunk's G, rotate Wt prefetch, then barrier
        if (c < 7) store_g(buf ^ 1, dn);
        wfn = wf2;
        __syncthreads();
    }

    // ---- epilogue: D[p][sample]: col = sample; lane & lane^32 share a sample.
#pragma unroll
    for (int r2 = 0; r2 < 2; ++r2) {
        float s = 0.0f;
#pragma unroll
        for (int pt = 0; pt < 2; ++pt)
#pragma unroll
            for (int e = 0; e < 16; ++e) s += acc[pt][r2][e] * acc[pt][r2][e];
        s += __shfl_xor(s, 32);
        if (lane < 32) red[w][r2][lane] = s;
    }
    __syncthreads();

    if (tid < 64) {
        const int li = tid & 31, rr = tid >> 5;
        float q = 6.0f * (red[0][rr][li] + red[1][rr][li] + red[2][rr][li] + red[3][rr][li]);
        float n = sqrtf(q + 1e-10f);
        float d = n - KAPPA;
        float a = d * d, b = n;
#pragma unroll
        for (int m = 1; m <= 32; m <<= 1) {
            a += __shfl_xor(a, m);
            b += __shfl_xor(b, m);
        }
        if (tid == 0) {
            partials[blk]        = a;
            partials[NBLK + blk] = b;
        }
    }
}

// ---------------------------------------------------------------------------
// Kernel 3: finalize — deterministic sum of 512 per-block partials.
// ---------------------------------------------------------------------------
__global__ void finalize_k(const float* __restrict__ partials, float* __restrict__ out) {
    __shared__ float sl[256], sn[256];
    int tid = threadIdx.x;
    sl[tid] = partials[tid] + partials[tid + 256];
    sn[tid] = partials[NBLK + tid] + partials[NBLK + tid + 256];
    __syncthreads();
    for (int st = 128; st > 0; st >>= 1) {
        if (tid < st) { sl[tid] += sl[tid + st]; sn[tid] += sn[tid + st]; }
        __syncthreads();
    }
    if (tid == 0) {
        out[0] = sl[0] / 32768.0f;
        out[1] = sn[0] / 32768.0f;
    }
}

// ---------------------------------------------------------------------------
extern "C" void kernel_launch(void* const* d_in, const int* in_sizes, int n_in,
                              void* d_out, int out_size, void* d_ws, size_t ws_size,
                              hipStream_t stream) {
    const float* x  = (const float*)d_in[0];
    const float* W1 = (const float*)d_in[1];
    const float* b1 = (const float*)d_in[2];
    const float* W2 = (const float*)d_in[3];
    // b2 (d_in[4]) unused: the Jacobian kills the bias.

    bf16x8* V        = (bf16x8*)d_ws;          // 16384 frags * 16 B = 256 KB
    bf16x8* Wt       = V + 16384;              // 1024 frags * 16 B = 16 KB
    float*  partials = (float*)(Wt + 1024);    // 1024 floats

    build_v<<<68, 256, 0, stream>>>(W1, W2, b1, V, Wt);
    torsion_main<<<NBLK, 256, 0, stream>>>(x, V, Wt, partials);
    finalize_k<<<1, 256, 0, stream>>>(partials, (float*)d_out);
}